// Round 1
// baseline (454.553 us; speedup 1.0000x reference)
//
#include <hip/hip_runtime.h>
#include <hip/hip_bf16.h>

typedef unsigned short u16;
typedef unsigned int u32;
typedef __bf16 bf16x8 __attribute__((ext_vector_type(8)));
typedef float f32x4 __attribute__((ext_vector_type(4)));

#define N_ 32
#define D_ 512
#define P_ 3136   // 56*56
#define K_ 64
#define TILES_P 49          // 3136 / 64
#define NDP (D_ * P_)       // 1605632

// ---- workspace layout (bytes) ----
// wbf   : bf16 conv_w [64][512]                      @ 0        (65536)
// a_ws  : bf16 a' [32][64][3136]                     @ 65536    (12845056)
// a_sum : f32 [32][64]                               @ 12910592 (8192)
// agg   : f32 agg_part [2][32][64][512]              @ 12918784 (8388608)
// total : 21307392

__device__ __forceinline__ u16 f2bf(float f) {       // RNE float->bf16 bits
  u32 u = __float_as_uint(f);
  return (u16)((u + 0x7fffu + ((u >> 16) & 1u)) >> 16);
}
__device__ __forceinline__ u32 pack2(float a, float b) {
  return (u32)f2bf(a) | ((u32)f2bf(b) << 16);
}

// -------- KW: conv_w fp32 -> bf16 (64KB, L2-resident for K1) --------
__global__ __launch_bounds__(256) void kw_kernel(const float* __restrict__ w,
                                                 u16* __restrict__ wbf) {
  int i = blockIdx.x * 256 + threadIdx.x;            // 8192 threads * 4 elems
  float4 v = ((const float4*)w)[i];
  ((uint2*)wbf)[i] = make_uint2(pack2(v.x, v.y), pack2(v.z, v.w));
}

// -------- K1: logits GEMM + softmax -> a' (bf16), a_sum --------
// block = (n, 64-pixel tile); 256 thr = 4 waves; wave w owns 16 pixels.
__global__ __launch_bounds__(256) void k1_kernel(const float* __restrict__ x,
                                                 const u16* __restrict__ wbf,
                                                 u16* __restrict__ a_ws,
                                                 float* __restrict__ a_sum) {
  __shared__ u16 lds_x[64 * 32];        // [p][swizzled 8-d chunk], 4KB per K-step
  __shared__ float a_stage[64][65];     // [k][p] softmax result (f32)
  __shared__ float red[4][64];          // sumsq partials
  __shared__ float invn_s[64];          // 1/max(||x_p||,eps)

  const int t = threadIdx.x;
  const int bid = blockIdx.x;
  const int n = bid / TILES_P;
  const int tile = bid - n * TILES_P;
  const int p0 = tile * 64;
  const int lane = t & 63;
  const int w = t >> 6;                 // wave id == staging d-chunk
  const int c = lane & 15;
  const int q = lane >> 4;

  // staging: thread t always loads pixel p = lane (sumsq stays in 1 register)
  const float* xb = x + (size_t)n * NDP + p0 + lane;
  const int wslot = w ^ ((lane >> 1) & 3);      // XOR swizzle: 2-way max banks
  // mfma read side: wave w reads pixel rp, chunk q
  const int rp = w * 16 + c;
  const int rslot = q ^ ((rp >> 1) & 3);

  f32x4 acc[4];
#pragma unroll
  for (int m = 0; m < 4; ++m) acc[m] = (f32x4){0.f, 0.f, 0.f, 0.f};
  float sumsq = 0.f;

  for (int s = 0; s < 16; ++s) {        // K-loop: d-step of 32
    const float* xs = xb + (s * 32 + w * 8) * P_;
    float v[8];
#pragma unroll
    for (int j = 0; j < 8; ++j) v[j] = xs[j * P_];   // 256B coalesced per wave
#pragma unroll
    for (int j = 0; j < 8; ++j) sumsq += v[j] * v[j];
    uint4 pk = make_uint4(pack2(v[0], v[1]), pack2(v[2], v[3]),
                          pack2(v[4], v[5]), pack2(v[6], v[7]));
    __syncthreads();                    // previous step's ds_reads done
    ((uint4*)lds_x)[lane * 4 + wslot] = pk;
    __syncthreads();
    bf16x8 bfrag = ((const bf16x8*)lds_x)[rp * 4 + rslot];
#pragma unroll
    for (int m = 0; m < 4; ++m) {
      bf16x8 afrag = ((const bf16x8*)wbf)[(m * 16 + c) * 64 + s * 4 + q];
      acc[m] = __builtin_amdgcn_mfma_f32_16x16x32_bf16(afrag, bfrag, acc[m], 0, 0, 0);
    }
  }

  // per-pixel inv-norm: reduce 4 d-chunk partials
  red[w][lane] = sumsq;
  __syncthreads();
  if (t < 64) {
    float s2 = red[0][t] + red[1][t] + red[2][t] + red[3][t];
    invn_s[t] = 1.f / fmaxf(sqrtf(s2), 1e-12f);
  }
  __syncthreads();

  // softmax over k: wave w holds all 64 k for its 16 pixels.
  // lane (q,c): k = m*16 + q*4 + r, pixel rp = w*16 + c  -> reduce over lane bits 4,5
  const float inv_p = invn_s[rp];
  float sc[4][4];
  float lmax = -3.0e38f;
#pragma unroll
  for (int m = 0; m < 4; ++m)
#pragma unroll
    for (int r = 0; r < 4; ++r) {
      float val = acc[m][r] * inv_p;
      sc[m][r] = val;
      lmax = fmaxf(lmax, val);
    }
  lmax = fmaxf(lmax, __shfl_xor(lmax, 16));
  lmax = fmaxf(lmax, __shfl_xor(lmax, 32));
  float lsum = 0.f;
#pragma unroll
  for (int m = 0; m < 4; ++m)
#pragma unroll
    for (int r = 0; r < 4; ++r) {
      float e = __expf(sc[m][r] - lmax);
      sc[m][r] = e;
      lsum += e;
    }
  lsum += __shfl_xor(lsum, 16);
  lsum += __shfl_xor(lsum, 32);
  const float rs = 1.f / lsum;
#pragma unroll
  for (int m = 0; m < 4; ++m)
#pragma unroll
    for (int r = 0; r < 4; ++r)
      a_stage[m * 16 + q * 4 + r][rp] = sc[m][r] * rs;   // a (pre inv_n)
  __syncthreads();

  // write a' = a*inv_n as bf16 (coalesced 32B/thread) + a_sum atomics
  {
    const int k = t >> 2, pc = t & 3;
    float ssum = 0.f;
    u32 u[8];
#pragma unroll
    for (int jj = 0; jj < 8; ++jj) {
      int p = pc * 16 + jj * 2;
      float a0 = a_stage[k][p], a1 = a_stage[k][p + 1];
      ssum += a0 + a1;
      u[jj] = (u32)f2bf(a0 * invn_s[p]) | ((u32)f2bf(a1 * invn_s[p + 1]) << 16);
    }
    u16* dst = a_ws + (size_t)n * (K_ * P_) + k * P_ + p0 + pc * 16;
    ((uint4*)dst)[0] = make_uint4(u[0], u[1], u[2], u[3]);
    ((uint4*)dst)[1] = make_uint4(u[4], u[5], u[6], u[7]);
    ssum += __shfl_xor(ssum, 1);
    ssum += __shfl_xor(ssum, 2);
    if ((t & 3) == 0) atomicAdd(&a_sum[n * 64 + k], ssum);
  }
}

// -------- K2: agg[k,d] = sum_p a'[k,p] * x[d,p] (both operands direct from
// global in fragment layout; no LDS, no barriers). split-2 over p. --------
__global__ __launch_bounds__(256) void k2_kernel(const float* __restrict__ x,
                                                 const u16* __restrict__ a_ws,
                                                 float* __restrict__ agg) {
  const int bid = blockIdx.x;           // 512 = 32n * 8dblk * 2pp
  const int n = bid >> 4;
  const int dblk = (bid >> 1) & 7;
  const int pp = bid & 1;
  const int t = threadIdx.x;
  const int lane = t & 63, w = t >> 6;
  const int c = lane & 15, q = lane >> 4;
  const int d0 = dblk * 64 + w * 16;    // wave owns 16 d columns

  f32x4 acc[4];
#pragma unroll
  for (int m = 0; m < 4; ++m) acc[m] = (f32x4){0.f, 0.f, 0.f, 0.f};

  const bf16x8* arow = (const bf16x8*)(a_ws + (size_t)n * (K_ * P_)); // 392 frags/row
  const float4* xf = (const float4*)(x + ((size_t)n * D_ + d0 + c) * P_);
  const int it0 = pp * 49, it1 = it0 + 49;     // 98 K-steps of 32 total
  for (int it = it0; it < it1; ++it) {
    float4 b0 = xf[it * 8 + q * 2];
    float4 b1 = xf[it * 8 + q * 2 + 1];
    bf16x8 bfrag;
    bfrag[0] = (__bf16)b0.x; bfrag[1] = (__bf16)b0.y;
    bfrag[2] = (__bf16)b0.z; bfrag[3] = (__bf16)b0.w;
    bfrag[4] = (__bf16)b1.x; bfrag[5] = (__bf16)b1.y;
    bfrag[6] = (__bf16)b1.z; bfrag[7] = (__bf16)b1.w;
#pragma unroll
    for (int m = 0; m < 4; ++m) {
      bf16x8 afrag = arow[(m * 16 + c) * 392 + it * 4 + q];
      acc[m] = __builtin_amdgcn_mfma_f32_16x16x32_bf16(afrag, bfrag, acc[m], 0, 0, 0);
    }
  }
  float* ob = agg + ((size_t)pp * 32 + n) * (K_ * D_);
#pragma unroll
  for (int m = 0; m < 4; ++m)
#pragma unroll
    for (int r = 0; r < 4; ++r)
      ob[(m * 16 + q * 4 + r) * D_ + d0 + c] = acc[m][r];
}

// -------- K3: vlad = agg0+agg1 - a_sum*c ; intra + global L2 normalize ------
__global__ __launch_bounds__(256) void k3_kernel(const float* __restrict__ agg,
                                                 const float* __restrict__ a_sum,
                                                 const float* __restrict__ cent,
                                                 float* __restrict__ out) {
  __shared__ float rowsq[64][4];
  __shared__ float invr[64];
  __shared__ float ginv_s;
  const int n = blockIdx.x;
  const int t = threadIdx.x;
  const int w = t >> 6;
  const float* a0 = agg + (size_t)n * 32768;
  const float* a1 = a0 + 32 * 32768;
  float* o = out + (size_t)n * 32768;
  float s0 = 0.f;
  for (int i = 0; i < 128; ++i) {
    const int e = t + (i << 8);
    const int k = i >> 1;                       // all 64 lanes share k
    float v = a0[e] + a1[e] - a_sum[n * 64 + k] * cent[e];
    o[e] = v;
    float v2 = v * v;
    v2 += __shfl_xor(v2, 1);  v2 += __shfl_xor(v2, 2);  v2 += __shfl_xor(v2, 4);
    v2 += __shfl_xor(v2, 8);  v2 += __shfl_xor(v2, 16); v2 += __shfl_xor(v2, 32);
    if (i & 1) { if ((t & 63) == 0) rowsq[k][w] = s0 + v2; }
    else s0 = v2;
  }
  __syncthreads();
  if (t < 64) {                                  // one wave
    float row = rowsq[t][0] + rowsq[t][1] + rowsq[t][2] + rowsq[t][3];
    float ri = 1.f / fmaxf(sqrtf(row), 1e-12f);
    invr[t] = ri;
    float g = row * ri * ri;                     // normalized-row sumsq
    g += __shfl_xor(g, 1); g += __shfl_xor(g, 2); g += __shfl_xor(g, 4);
    g += __shfl_xor(g, 8); g += __shfl_xor(g, 16); g += __shfl_xor(g, 32);
    if (t == 0) ginv_s = 1.f / fmaxf(sqrtf(g), 1e-12f);
  }
  __syncthreads();
  const float gi = ginv_s;
  for (int i = 0; i < 128; ++i) {
    const int e = t + (i << 8);
    o[e] *= invr[i >> 1] * gi;                   // each thread re-scales its own writes
  }
}

extern "C" void kernel_launch(void* const* d_in, const int* in_sizes, int n_in,
                              void* d_out, int out_size, void* d_ws, size_t ws_size,
                              hipStream_t stream) {
  (void)in_sizes; (void)n_in; (void)out_size; (void)ws_size;
  const float* x    = (const float*)d_in[0];
  const float* cw   = (const float*)d_in[1];
  const float* cent = (const float*)d_in[2];
  float* out = (float*)d_out;
  char* ws = (char*)d_ws;
  u16*   wbf   = (u16*)(ws);
  u16*   a_ws  = (u16*)(ws + 65536);
  float* a_sum = (float*)(ws + 12910592);
  float* agg   = (float*)(ws + 12918784);

  hipMemsetAsync(a_sum, 0, 64 * 32 * sizeof(float), stream);  // atomics target
  kw_kernel<<<32, 256, 0, stream>>>(cw, wbf);
  k1_kernel<<<32 * TILES_P, 256, 0, stream>>>(x, wbf, a_ws, a_sum);
  k2_kernel<<<512, 256, 0, stream>>>(x, a_ws, agg);
  k3_kernel<<<32, 256, 0, stream>>>(agg, a_sum, cent, out);
}

// Round 2
// 393.930 us; speedup vs baseline: 1.1539x; 1.1539x over previous
//
#include <hip/hip_runtime.h>
#include <hip/hip_bf16.h>

typedef unsigned short u16;
typedef unsigned int u32;
typedef __bf16 bf16x8 __attribute__((ext_vector_type(8)));
typedef float f32x4 __attribute__((ext_vector_type(4)));

#define N_ 32
#define D_ 512
#define P_ 3136   // 56*56
#define K_ 64
#define TILES_P 49          // 3136 / 64
#define NDP (D_ * P_)       // 1605632

// ---- workspace layout (bytes) ----
// wbf   : bf16 conv_w [64][512]                      @ 0        (65536)
// a_ws  : bf16 a' [32][64][3136]                     @ 65536    (12845056)
// a_sum : f32 [32][64]                               @ 12910592 (8192)
// agg   : f32 agg_part [7][32][64][512]              @ 12918784 (29360128)
// rowsq : f32 [32][64]                               @ 42278912 (8192)

__device__ __forceinline__ u16 f2bf(float f) {       // RNE float->bf16 bits
  u32 u = __float_as_uint(f);
  return (u16)((u + 0x7fffu + ((u >> 16) & 1u)) >> 16);
}
__device__ __forceinline__ u32 pack2(float a, float b) {
  return (u32)f2bf(a) | ((u32)f2bf(b) << 16);
}

// -------- KW: conv_w fp32 -> bf16 (64KB, L2-resident for K1) --------
__global__ __launch_bounds__(256) void kw_kernel(const float* __restrict__ w,
                                                 u16* __restrict__ wbf) {
  int i = blockIdx.x * 256 + threadIdx.x;            // 8192 threads * 4 elems
  float4 v = ((const float4*)w)[i];
  ((uint2*)wbf)[i] = make_uint2(pack2(v.x, v.y), pack2(v.z, v.w));
}

// -------- K1: logits GEMM + softmax -> a' (bf16), a_sum --------
// block = (n, 64-pixel tile); 4 waves; wave w owns pixels w*16..w*16+15.
// B-frags loaded DIRECTLY from global (no LDS staging, no K-loop barriers):
// lane (q,c) of wave w loads x[d = s*32+q*8+j][p = w*16+c] -> per instruction
// 4 rows x 64B contiguous segments, fully coalesced.
__global__ __launch_bounds__(256) void k1_kernel(const float* __restrict__ x,
                                                 const u16* __restrict__ wbf,
                                                 u16* __restrict__ a_ws,
                                                 float* __restrict__ a_sum) {
  __shared__ float a_stage[64][65];     // [k][p] softmax result (f32)
  __shared__ float invn_s[64];          // 1/max(||x_p||,eps)

  const int t = threadIdx.x;
  const int bid = blockIdx.x;
  const int n = bid / TILES_P;
  const int tile = bid - n * TILES_P;
  const int p0 = tile * 64;
  const int lane = t & 63;
  const int w = t >> 6;
  const int c = lane & 15;
  const int q = lane >> 4;
  const int rp = w * 16 + c;            // pixel this lane serves

  const float* xl = x + (size_t)n * NDP + p0 + rp + (size_t)(q * 8) * P_;

  f32x4 acc[4];
#pragma unroll
  for (int m = 0; m < 4; ++m) acc[m] = (f32x4){0.f, 0.f, 0.f, 0.f};
  float sumsq = 0.f;

  float v[8];
#pragma unroll
  for (int j = 0; j < 8; ++j) v[j] = xl[j * P_];

  for (int s = 0; s < 16; ++s) {        // K-loop: d-step of 32, NO barriers
    float vn[8];
    if (s < 15) {
      const float* xs = xl + (size_t)((s + 1) * 32) * P_;
#pragma unroll
      for (int j = 0; j < 8; ++j) vn[j] = xs[j * P_];
    }
    bf16x8 bfrag;
#pragma unroll
    for (int j = 0; j < 8; ++j) {
      sumsq += v[j] * v[j];
      bfrag[j] = (__bf16)v[j];
    }
#pragma unroll
    for (int m = 0; m < 4; ++m) {
      bf16x8 afrag = ((const bf16x8*)wbf)[(m * 16 + c) * 64 + s * 4 + q];
      acc[m] = __builtin_amdgcn_mfma_f32_16x16x32_bf16(afrag, bfrag, acc[m], 0, 0, 0);
    }
    if (s < 15) {
#pragma unroll
      for (int j = 0; j < 8; ++j) v[j] = vn[j];
    }
  }

  // per-pixel inv-norm: lane holds d-chunks for q; reduce over lane bits 4,5
  sumsq += __shfl_xor(sumsq, 16);
  sumsq += __shfl_xor(sumsq, 32);
  const float inv_p = 1.f / fmaxf(sqrtf(sumsq), 1e-12f);
  if (q == 0) invn_s[rp] = inv_p;

  // softmax over k: lanes (q, fixed w,c) + regs (m,r) hold all 64 k of pixel rp
  float sc[4][4];
  float lmax = -3.0e38f;
#pragma unroll
  for (int m = 0; m < 4; ++m)
#pragma unroll
    for (int r = 0; r < 4; ++r) {
      float val = acc[m][r] * inv_p;
      sc[m][r] = val;
      lmax = fmaxf(lmax, val);
    }
  lmax = fmaxf(lmax, __shfl_xor(lmax, 16));
  lmax = fmaxf(lmax, __shfl_xor(lmax, 32));
  float lsum = 0.f;
#pragma unroll
  for (int m = 0; m < 4; ++m)
#pragma unroll
    for (int r = 0; r < 4; ++r) {
      float e = __expf(sc[m][r] - lmax);
      sc[m][r] = e;
      lsum += e;
    }
  lsum += __shfl_xor(lsum, 16);
  lsum += __shfl_xor(lsum, 32);
  const float rs = 1.f / lsum;
#pragma unroll
  for (int m = 0; m < 4; ++m)
#pragma unroll
    for (int r = 0; r < 4; ++r)
      a_stage[m * 16 + q * 4 + r][rp] = sc[m][r] * rs;   // a (pre inv_n)
  __syncthreads();                      // the ONLY barrier in K1

  // write a' = a*inv_n as bf16 (coalesced 32B/thread) + a_sum atomics
  {
    const int k = t >> 2, pc = t & 3;
    float ssum = 0.f;
    u32 u[8];
#pragma unroll
    for (int jj = 0; jj < 8; ++jj) {
      int p = pc * 16 + jj * 2;
      float a0 = a_stage[k][p], a1 = a_stage[k][p + 1];
      ssum += a0 + a1;
      u[jj] = (u32)f2bf(a0 * invn_s[p]) | ((u32)f2bf(a1 * invn_s[p + 1]) << 16);
    }
    u16* dst = a_ws + (size_t)n * (K_ * P_) + k * P_ + p0 + pc * 16;
    ((uint4*)dst)[0] = make_uint4(u[0], u[1], u[2], u[3]);
    ((uint4*)dst)[1] = make_uint4(u[4], u[5], u[6], u[7]);
    ssum += __shfl_xor(ssum, 1);
    ssum += __shfl_xor(ssum, 2);
    if ((t & 3) == 0) atomicAdd(&a_sum[n * 64 + k], ssum);
  }
}

// -------- K2: agg[k,d] = sum_p a'[k,p] * x[d,p]; no LDS, no barriers,
// next-iter prefetch; split-7 over p (98 = 7*14 K-steps). --------
__global__ __launch_bounds__(256) void k2_kernel(const float* __restrict__ x,
                                                 const u16* __restrict__ a_ws,
                                                 float* __restrict__ agg) {
  const int bid = blockIdx.x;           // 1792 = 32n * 8dblk * 7pp
  const int n = bid / 56;
  const int rem = bid - n * 56;
  const int dblk = rem / 7;
  const int pp = rem - dblk * 7;
  const int t = threadIdx.x;
  const int lane = t & 63, w = t >> 6;
  const int c = lane & 15, q = lane >> 4;
  const int d0 = dblk * 64 + w * 16;    // wave owns 16 d columns

  f32x4 acc[4];
#pragma unroll
  for (int m = 0; m < 4; ++m) acc[m] = (f32x4){0.f, 0.f, 0.f, 0.f};

  const bf16x8* arow = (const bf16x8*)(a_ws + (size_t)n * (K_ * P_)); // 392 frags/row
  const float4* xf = (const float4*)(x + ((size_t)n * D_ + d0 + c) * P_);
  const int it0 = pp * 14, it1 = it0 + 14;

  float4 b0 = xf[it0 * 8 + q * 2];
  float4 b1 = xf[it0 * 8 + q * 2 + 1];
  bf16x8 af0 = arow[(0 * 16 + c) * 392 + it0 * 4 + q];
  bf16x8 af1 = arow[(1 * 16 + c) * 392 + it0 * 4 + q];
  bf16x8 af2 = arow[(2 * 16 + c) * 392 + it0 * 4 + q];
  bf16x8 af3 = arow[(3 * 16 + c) * 392 + it0 * 4 + q];

#pragma unroll
  for (int it = it0; it < it1; ++it) {
    float4 nb0, nb1;
    bf16x8 nf0, nf1, nf2, nf3;
    if (it + 1 < it1) {
      nb0 = xf[(it + 1) * 8 + q * 2];
      nb1 = xf[(it + 1) * 8 + q * 2 + 1];
      nf0 = arow[(0 * 16 + c) * 392 + (it + 1) * 4 + q];
      nf1 = arow[(1 * 16 + c) * 392 + (it + 1) * 4 + q];
      nf2 = arow[(2 * 16 + c) * 392 + (it + 1) * 4 + q];
      nf3 = arow[(3 * 16 + c) * 392 + (it + 1) * 4 + q];
    }
    bf16x8 bfrag;
    bfrag[0] = (__bf16)b0.x; bfrag[1] = (__bf16)b0.y;
    bfrag[2] = (__bf16)b0.z; bfrag[3] = (__bf16)b0.w;
    bfrag[4] = (__bf16)b1.x; bfrag[5] = (__bf16)b1.y;
    bfrag[6] = (__bf16)b1.z; bfrag[7] = (__bf16)b1.w;
    acc[0] = __builtin_amdgcn_mfma_f32_16x16x32_bf16(af0, bfrag, acc[0], 0, 0, 0);
    acc[1] = __builtin_amdgcn_mfma_f32_16x16x32_bf16(af1, bfrag, acc[1], 0, 0, 0);
    acc[2] = __builtin_amdgcn_mfma_f32_16x16x32_bf16(af2, bfrag, acc[2], 0, 0, 0);
    acc[3] = __builtin_amdgcn_mfma_f32_16x16x32_bf16(af3, bfrag, acc[3], 0, 0, 0);
    if (it + 1 < it1) {
      b0 = nb0; b1 = nb1; af0 = nf0; af1 = nf1; af2 = nf2; af3 = nf3;
    }
  }
  float* ob = agg + ((size_t)pp * 32 + n) * (K_ * D_);
#pragma unroll
  for (int m = 0; m < 4; ++m)
#pragma unroll
    for (int r = 0; r < 4; ++r)
      ob[(m * 16 + q * 4 + r) * D_ + d0 + c] = acc[m][r];
}

// -------- K3a: vlad = sum_pp agg[pp] - a_sum*c ; per-row sumsq --------
// one wave per (n,k) row of 512 floats.
__global__ __launch_bounds__(64) void k3a_kernel(const float* __restrict__ agg,
                                                 const float* __restrict__ a_sum,
                                                 const float* __restrict__ cent,
                                                 float* __restrict__ out,
                                                 float* __restrict__ rowsq) {
  const int b = blockIdx.x;             // n*64 + k
  const int n = b >> 6, k = b & 63;
  const int t = threadIdx.x;            // 64 lanes, 8 floats each
  const float* ab = agg + ((size_t)n * 64 + k) * 512 + t * 8;
  float v[8];
#pragma unroll
  for (int j = 0; j < 8; ++j) v[j] = 0.f;
#pragma unroll
  for (int pp = 0; pp < 7; ++pp) {
    const float4* p4 = (const float4*)(ab + (size_t)pp * 32 * (K_ * D_));
    float4 r0 = p4[0], r1 = p4[1];
    v[0] += r0.x; v[1] += r0.y; v[2] += r0.z; v[3] += r0.w;
    v[4] += r1.x; v[5] += r1.y; v[6] += r1.z; v[7] += r1.w;
  }
  const float asum = a_sum[b];
  const float4* c4 = (const float4*)(cent + k * 512 + t * 8);
  float4 c0 = c4[0], c1 = c4[1];
  v[0] -= asum * c0.x; v[1] -= asum * c0.y; v[2] -= asum * c0.z; v[3] -= asum * c0.w;
  v[4] -= asum * c1.x; v[5] -= asum * c1.y; v[6] -= asum * c1.z; v[7] -= asum * c1.w;
  float ss = 0.f;
#pragma unroll
  for (int j = 0; j < 8; ++j) ss += v[j] * v[j];
  ss += __shfl_xor(ss, 1);  ss += __shfl_xor(ss, 2);  ss += __shfl_xor(ss, 4);
  ss += __shfl_xor(ss, 8);  ss += __shfl_xor(ss, 16); ss += __shfl_xor(ss, 32);
  float4* o4 = (float4*)(out + (size_t)n * 32768 + k * 512 + t * 8);
  o4[0] = make_float4(v[0], v[1], v[2], v[3]);
  o4[1] = make_float4(v[4], v[5], v[6], v[7]);
  if (t == 0) rowsq[b] = ss;
}

// -------- K3b: intra + global normalize (scale in place) --------
__global__ __launch_bounds__(256) void k3b_kernel(const float* __restrict__ rowsq,
                                                  float* __restrict__ out) {
  __shared__ float invr_s[64];
  __shared__ float gi_s;
  const int n = blockIdx.x >> 3;
  const int seg = blockIdx.x & 7;       // 4096 floats per segment
  const int t = threadIdx.x;
  if (t < 64) {
    float r = rowsq[n * 64 + t];
    float ri = 1.f / fmaxf(sqrtf(r), 1e-12f);
    invr_s[t] = ri;
    float g = r * ri * ri;
    g += __shfl_xor(g, 1); g += __shfl_xor(g, 2); g += __shfl_xor(g, 4);
    g += __shfl_xor(g, 8); g += __shfl_xor(g, 16); g += __shfl_xor(g, 32);
    if (t == 0) gi_s = 1.f / fmaxf(sqrtf(g), 1e-12f);
  }
  __syncthreads();
  const int e0 = seg * 4096 + t * 16;   // 16 consecutive floats, same k (16|512)
  const float sc = invr_s[e0 >> 9] * gi_s;
  float4* o4 = (float4*)(out + (size_t)n * 32768 + e0);
#pragma unroll
  for (int i = 0; i < 4; ++i) {
    float4 vv = o4[i];
    vv.x *= sc; vv.y *= sc; vv.z *= sc; vv.w *= sc;
    o4[i] = vv;
  }
}

extern "C" void kernel_launch(void* const* d_in, const int* in_sizes, int n_in,
                              void* d_out, int out_size, void* d_ws, size_t ws_size,
                              hipStream_t stream) {
  (void)in_sizes; (void)n_in; (void)out_size; (void)ws_size;
  const float* x    = (const float*)d_in[0];
  const float* cw   = (const float*)d_in[1];
  const float* cent = (const float*)d_in[2];
  float* out = (float*)d_out;
  char* ws = (char*)d_ws;
  u16*   wbf   = (u16*)(ws);
  u16*   a_ws  = (u16*)(ws + 65536);
  float* a_sum = (float*)(ws + 12910592);
  float* agg   = (float*)(ws + 12918784);
  float* rowsq = (float*)(ws + 42278912);

  hipMemsetAsync(a_sum, 0, 64 * 32 * sizeof(float), stream);  // atomics target
  kw_kernel<<<32, 256, 0, stream>>>(cw, wbf);
  k1_kernel<<<32 * TILES_P, 256, 0, stream>>>(x, wbf, a_ws, a_sum);
  k2_kernel<<<1792, 256, 0, stream>>>(x, a_ws, agg);
  k3a_kernel<<<2048, 64, 0, stream>>>(agg, a_sum, cent, out, rowsq);
  k3b_kernel<<<256, 256, 0, stream>>>(rowsq, out);
}